// Round 15
// baseline (225.909 us; speedup 1.0000x reference)
//
#include <hip/hip_runtime.h>
#include <hip/hip_bf16.h>
#include <stdint.h>

// Attention (non-causal): B=2 H=16 S=2048 D=64, fp32 in/out.
// R15 = R11 main loop + prepass FUSED into the attn kernel behind a per-bh
// spin gate: each block converts its 2 K-tiles (flat fp32->bf16) and 2
// V-tiles (LDS transpose) of its own bh, threadfence + atomicAdd(gate[bh]),
// then spins until all 16 same-bh blocks are done (they share an XCD via the
// block swizzle -> converted tiles are L2-local). Grid 512 = 2 blocks/CU
// (LDS 64KB) x 256 CU -> all blocks co-resident, spin cannot deadlock.
// gate[] zeroed each call via hipMemsetAsync (graph-capturable).
// Main loop = R11: 8 waves x 32 q-rows, KV parity split, 32x32x16 MFMA,
// fixed-offset softmax (exp2), in-register P via cvt_pk+permlane32_swap,
// gload_lds staging w/ XOR source swizzle, 16 MFMA per barrier-period.

#define B_ 2
#define H_ 16
#define S_ 2048
#define D_ 64
#define BH_ (B_ * H_)
#define QBLK 128
#define KVBLK 64
#define NKV (S_ / KVBLK)   // 32
#define NPER (NKV / 2)     // 16 periods, 2 tiles each

typedef __bf16 bf16_t;
typedef bf16_t bf16x8 __attribute__((ext_vector_type(8)));
typedef bf16_t bf16x4 __attribute__((ext_vector_type(4)));
typedef float f32x16 __attribute__((ext_vector_type(16)));
typedef uint32_t u32;

__device__ __forceinline__ f32x16 mfma32(bf16x8 a, bf16x8 b, f32x16 c) {
  return __builtin_amdgcn_mfma_f32_32x32x16_bf16(a, b, c, 0, 0, 0);
}

// pack two f32 -> u32 of 2 bf16 (lo in low 16 bits). No builtin on gfx950.
__device__ __forceinline__ u32 cvt_pk_bf16(float lo, float hi) {
  u32 r;
  asm("v_cvt_pk_bf16_f32 %0, %1, %2" : "=v"(r) : "v"(lo), "v"(hi));
  return r;
}

// v_permlane32_swap_b32 x, y: swaps x's lanes 32-63 with y's lanes 0-31.
__device__ __forceinline__ void swap32(u32& x, u32& y) {
  asm("v_permlane32_swap_b32 %0, %1" : "+v"(x), "+v"(y));
}

// async global->LDS, 16B per lane. LDS dest is wave-uniform base + lane*16.
__device__ __forceinline__ void gload_lds16(const bf16_t* g, bf16_t* l) {
  __builtin_amdgcn_global_load_lds(
      (const __attribute__((address_space(1))) unsigned int*)g,
      (__attribute__((address_space(3))) unsigned int*)l, 16, 0, 0);
}

// Main kernel. 512 threads = 8 waves; wave (wq, wkv) owns q-rows wq*32..+31
// and KV tiles of parity wkv. 32x32x16 MFMA layouts (m74/m101):
//   A: lane holds A[lane&31][(lane>>5)*8 + j]; B: B[(lane>>5)*8+j][lane&31]
//   C/D: lane holds D[(reg&3) + 8*(reg>>2) + 4*(lane>>5)][lane&31]
// Swapped QK^T: S^T[kv][q] = mfma(A=K, B=Q^T) -> P per-lane for q = lane&31.
// PV transposed: O^T[d][q] = mfma(A=V^T, B=P^T); B-frag slot (hi,j) for
// k-step kt2 holds kv = 16*kt2 + 8*hi + j via the permlane32 half-exchange.
// XCD swizzle: bh = 4*(bid&7) + ((bid>>3)>>4), qt = (bid>>3)&15 (bijective):
// all 16 q-tile blocks of one bh land on one XCD.
__global__ __launch_bounds__(512, 4) void attn_kernel(
    const float* __restrict__ q, const float* __restrict__ kf,
    const float* __restrict__ vf, bf16_t* __restrict__ kb,
    bf16_t* __restrict__ vt, int* __restrict__ gate,
    float* __restrict__ out) {
  const int bid = blockIdx.x;
  const int g = bid >> 3;
  const int bh = 4 * (bid & 7) + (g >> 4);
  const int qt = g & 15;
  const int tid = threadIdx.x;
  const int wid = tid >> 6;
  const int lane = tid & 63;
  const int wq = wid & 3;    // q-group
  const int wkv = wid >> 2;  // kv parity group
  const int l31 = lane & 31; // q column (QK^T) / row index
  const int hi = lane >> 5;  // lane half

  // 64 KB: K bufs [4][64][64] + V bufs [4][64][64]; conversion scratch and
  // the epilogue alias the front.
  __shared__ __align__(16) char smem[65536];
  bf16_t* kbuf = (bf16_t*)smem;            // 4 x 4096 elems
  bf16_t* vbuf = (bf16_t*)(smem + 32768);  // 4 x 4096 elems
  float* epi = (float*)smem;               // [4][64][33] (epilogue, aliases)
  float (*vtile)[65] = (float(*)[65])smem; // 64x65 fp32 (conversion, aliases)

  // ---- Q B-fragments first (independent of gate; hides spin/convert time)
  const float qscale = 0.125f * 1.4426950408889634f;
  const int qrow = qt * QBLK + wq * 32 + l31;
  const float* qpr = q + ((size_t)bh * S_ + qrow) * D_;
  bf16x8 bq[4];
#pragma unroll
  for (int ks = 0; ks < 4; ++ks) {
    const float* p = qpr + ks * 16 + hi * 8;
    float4 x0 = *(const float4*)(p);
    float4 x1 = *(const float4*)(p + 4);
    bf16x8 a;
    a[0] = (bf16_t)(x0.x * qscale); a[1] = (bf16_t)(x0.y * qscale);
    a[2] = (bf16_t)(x0.z * qscale); a[3] = (bf16_t)(x0.w * qscale);
    a[4] = (bf16_t)(x1.x * qscale); a[5] = (bf16_t)(x1.y * qscale);
    a[6] = (bf16_t)(x1.z * qscale); a[7] = (bf16_t)(x1.w * qscale);
    bq[ks] = a;
  }

  // ---- conversion phase: this block converts K,V tiles 2qt, 2qt+1 of bh
#pragma unroll
  for (int tt = 0; tt < 2; ++tt) {
    const int t = 2 * qt + tt;
    // K tile: flat fp32 -> bf16, coalesced (1024 float4 / 512 threads)
    const float* src = kf + ((size_t)bh * S_ + (size_t)t * 64) * D_;
    bf16_t* dst = kb + ((size_t)bh * S_ + (size_t)t * 64) * D_;
#pragma unroll
    for (int i = 0; i < 2; ++i) {
      float4 x = ((const float4*)src)[i * 512 + tid];
      bf16x4 o = { (bf16_t)x.x, (bf16_t)x.y, (bf16_t)x.z, (bf16_t)x.w };
      ((bf16x4*)dst)[i * 512 + tid] = o;
    }
  }
#pragma unroll
  for (int tt = 0; tt < 2; ++tt) {
    const int t = 2 * qt + tt;
    // V tile: 64x64 transpose via LDS fp32 tile (pad 65 breaks conflicts)
    const float* vsrc = vf + ((size_t)bh * S_ + (size_t)t * 64) * D_;
    const int r0 = tid >> 4;          // 0..31
    const int c4 = (tid & 15) * 4;    // 0..60
    __syncthreads();  // vtile free (prev iter readers done)
#pragma unroll
    for (int p = 0; p < 2; ++p) {
      int r = r0 + p * 32;
      float4 x = *(const float4*)(vsrc + (size_t)r * D_ + c4);
      vtile[r][c4 + 0] = x.x; vtile[r][c4 + 1] = x.y;
      vtile[r][c4 + 2] = x.z; vtile[r][c4 + 3] = x.w;
    }
    __syncthreads();
    bf16_t* op = vt + (size_t)bh * D_ * S_ + (size_t)t * 64;
#pragma unroll
    for (int p = 0; p < 2; ++p) {
      int d = r0 + p * 32;
      bf16x4 o = { (bf16_t)vtile[c4 + 0][d], (bf16_t)vtile[c4 + 1][d],
                   (bf16_t)vtile[c4 + 2][d], (bf16_t)vtile[c4 + 3][d] };
      *(bf16x4*)(op + (size_t)d * S_ + c4) = o;
    }
  }
  __syncthreads();

  // ---- gate: release our tiles, wait for the other 15 blocks of this bh
  __threadfence();
  if (tid == 0) {
    atomicAdd(gate + bh, 1);
    while (atomicAdd(gate + bh, 0) < 16) __builtin_amdgcn_s_sleep(2);
  }
  __syncthreads();
  __threadfence();  // acquire: converted tiles visible (same-XCD L2)

  const bf16_t* kp = kb + (size_t)bh * S_ * D_;
  const bf16_t* vp = vt + (size_t)bh * D_ * S_;

  // staging geometry: thread covers 16B chunk tid of each 8KB tile
  const int srow = tid >> 3;
  const int scol = (tid & 7) ^ (srow & 7);  // XOR chunk swizzle (source side)
  const int kofs = srow * D_ + scol * 8;
  const size_t vofs = (size_t)srow * S_ + scol * 8;
  const int ldst = wid * 512;  // elems, wave-uniform dest (wave covers 512)

  float lsum = 0.f;
  f32x16 o0, o1;
#pragma unroll
  for (int r = 0; r < 16; ++r) { o0[r] = 0.f; o1[r] = 0.f; }

  // prologue: stage tiles 0,1 into parity-buf 0
#pragma unroll
  for (int par = 0; par < 2; ++par) {
    gload_lds16(kp + (size_t)par * (KVBLK * D_) + kofs, kbuf + par * 4096 + ldst);
    gload_lds16(vp + (size_t)par * KVBLK + vofs, vbuf + par * 4096 + ldst);
  }
  __syncthreads();

  for (int p = 0; p < NPER; ++p) {
    // stage next tile pair into the other parity buffers
    if (p + 1 < NPER) {
      const int nb = ((p + 1) & 1) * 2;
#pragma unroll
      for (int par = 0; par < 2; ++par) {
        const int t = 2 * p + 2 + par;
        gload_lds16(kp + (size_t)t * (KVBLK * D_) + kofs,
                    kbuf + (nb + par) * 4096 + ldst);
        gload_lds16(vp + (size_t)t * KVBLK + vofs,
                    vbuf + (nb + par) * 4096 + ldst);
      }
    }

    const bf16_t* kt_ = kbuf + ((p & 1) * 2 + wkv) * 4096;
    const bf16_t* vt_ = vbuf + ((p & 1) * 2 + wkv) * 4096;

    u32 w[2][8];
#pragma unroll
    for (int sub = 0; sub < 2; ++sub) {
      // QK^T: S^T[32 kv][32 q], K from LDS rows sub*32 + l31
      f32x16 sv;
#pragma unroll
      for (int r = 0; r < 16; ++r) sv[r] = 0.f;
#pragma unroll
      for (int ks = 0; ks < 4; ++ks) {
        const int row = sub * 32 + l31;
        const int ch = (2 * ks + hi) ^ (row & 7);
        bf16x8 a = *(const bf16x8*)(kt_ + row * D_ + ch * 8);
        sv = mfma32(a, bq[ks], sv);
      }
      // softmax (fixed offset): e = exp2(s); pack pairs to bf16 words
#pragma unroll
      for (int b = 0; b < 4; ++b) {
        float e0 = __builtin_amdgcn_exp2f(sv[4 * b + 0]);
        float e1 = __builtin_amdgcn_exp2f(sv[4 * b + 1]);
        float e2 = __builtin_amdgcn_exp2f(sv[4 * b + 2]);
        float e3 = __builtin_amdgcn_exp2f(sv[4 * b + 3]);
        lsum += (e0 + e1) + (e2 + e3);
        w[sub][2 * b + 0] = cvt_pk_bf16(e0, e1);
        w[sub][2 * b + 1] = cvt_pk_bf16(e2, e3);
      }
      // half-exchange so each lane holds its PV B-frag words
#pragma unroll
      for (int kt2 = 0; kt2 < 2; ++kt2) {
        swap32(w[sub][4 * kt2 + 0], w[sub][4 * kt2 + 2]);
        swap32(w[sub][4 * kt2 + 1], w[sub][4 * kt2 + 3]);
      }
    }

    // PV: O^T[d][q] += V^T[d][kv] * P^T[kv][q]
#pragma unroll
    for (int sub = 0; sub < 2; ++sub)
#pragma unroll
      for (int kt2 = 0; kt2 < 2; ++kt2) {
        union { u32 u[4]; bf16x8 v; } pb;
        pb.u[0] = w[sub][4 * kt2 + 0]; pb.u[1] = w[sub][4 * kt2 + 1];
        pb.u[2] = w[sub][4 * kt2 + 2]; pb.u[3] = w[sub][4 * kt2 + 3];
        {
          const int row = l31;  // dblk 0
          const int ch = (4 * sub + 2 * kt2 + hi) ^ (row & 7);
          bf16x8 a = *(const bf16x8*)(vt_ + row * KVBLK + ch * 8);
          o0 = mfma32(a, pb.v, o0);
        }
        {
          const int row = 32 + l31;  // dblk 1
          const int ch = (4 * sub + 2 * kt2 + hi) ^ (row & 7);
          bf16x8 a = *(const bf16x8*)(vt_ + row * KVBLK + ch * 8);
          o1 = mfma32(a, pb.v, o1);
        }
      }

    // barrier: drains vmcnt (next tiles staged) + all waves done with cur
    __syncthreads();
  }

  // ---- epilogue: combine kv-groups (pure addition: fixed-offset softmax)
  if (wkv == 1) {
    float* e = epi + ((size_t)wq * 64 + lane) * 33;
#pragma unroll
    for (int r = 0; r < 16; ++r) { e[r] = o0[r]; e[16 + r] = o1[r]; }
    e[32] = lsum;
  }
  __syncthreads();
  if (wkv == 0) {
    const float* e = epi + ((size_t)wq * 64 + lane) * 33;
#pragma unroll
    for (int r = 0; r < 16; ++r) { o0[r] += e[r]; o1[r] += e[16 + r]; }
    lsum += e[32];
    float ltot = lsum + __shfl_xor(lsum, 32, 64);
    float inv = 1.f / ltot;
    float* op = out + ((size_t)bh * S_ + qrow) * D_;
    // lane holds O^T[d = dblk*32 + 8b + 4hi + a][q = l31], a=0..3 consecutive
#pragma unroll
    for (int b = 0; b < 4; ++b) {
      float4 w0 = { o0[4 * b + 0] * inv, o0[4 * b + 1] * inv,
                    o0[4 * b + 2] * inv, o0[4 * b + 3] * inv };
      *(float4*)(op + 8 * b + 4 * hi) = w0;
      float4 w1 = { o1[4 * b + 0] * inv, o1[4 * b + 1] * inv,
                    o1[4 * b + 2] * inv, o1[4 * b + 3] * inv };
      *(float4*)(op + 32 + 8 * b + 4 * hi) = w1;
    }
  }
}

extern "C" void kernel_launch(void* const* d_in, const int* in_sizes, int n_in,
                              void* d_out, int out_size, void* d_ws, size_t ws_size,
                              hipStream_t stream) {
  const float* q = (const float*)d_in[0];
  const float* k = (const float*)d_in[1];
  const float* v = (const float*)d_in[2];
  float* out = (float*)d_out;

  // workspace: Kb (bf16 [BH][S][D]) + Vt (bf16 [BH][D][S]) + gate[BH]
  bf16_t* kb = (bf16_t*)d_ws;
  bf16_t* vt = kb + (size_t)BH_ * S_ * D_;
  int* gate = (int*)(vt + (size_t)BH_ * S_ * D_);

  hipMemsetAsync(gate, 0, BH_ * sizeof(int), stream);
  attn_kernel<<<dim3(BH_ * (S_ / QBLK)), 512, 0, stream>>>(q, k, v, kb, vt,
                                                           gate, out);
}

// Round 16
// 73.137 us; speedup vs baseline: 3.0888x; 3.0888x over previous
//
#include <hip/hip_runtime.h>
#include <hip/hip_bf16.h>
#include <stdint.h>

// Attention (non-causal): B=2 H=16 S=2048 D=64, fp32 in/out.
// R16 = R11 + in-kernel K conversion, T14 done right: K fp32 loads for the
// NEXT tile pair are issued at period start and pinned there by an
// asm volatile memory fence (R12's regression = compiler sank the loads to
// their use point at period end -> raw L2-latency stall before the barrier).
// cvt + swizzled ds_write_b128 happen after PV; the vmcnt wait lands ~a full
// period after issue. V keeps its prepass (transpose) + gload_lds staging.
// Rest = R11: 8 waves x 32 q-rows, KV parity split, 32x32x16 MFMA,
// fixed-offset softmax (exp2), in-register P via cvt_pk+permlane32_swap,
// XCD-aware block swizzle, 16 MFMA per wave per barrier-period.
// (R15 fused spin-gate: 226us convoy disaster — cross-block producer/
// consumer without cooperative launch is dead. R5/R9/R10/R13/R14: fatter
// waves, kv-half split, setprio, bank pad, cross-period PV all null/neg.)

#define B_ 2
#define H_ 16
#define S_ 2048
#define D_ 64
#define BH_ (B_ * H_)
#define QBLK 128
#define KVBLK 64
#define NKV (S_ / KVBLK)   // 32
#define NPER (NKV / 2)     // 16 periods, 2 tiles each

typedef __bf16 bf16_t;
typedef bf16_t bf16x8 __attribute__((ext_vector_type(8)));
typedef bf16_t bf16x4 __attribute__((ext_vector_type(4)));
typedef float f32x16 __attribute__((ext_vector_type(16)));
typedef uint32_t u32;

__device__ __forceinline__ f32x16 mfma32(bf16x8 a, bf16x8 b, f32x16 c) {
  return __builtin_amdgcn_mfma_f32_32x32x16_bf16(a, b, c, 0, 0, 0);
}

// pack two f32 -> u32 of 2 bf16 (lo in low 16 bits). No builtin on gfx950.
__device__ __forceinline__ u32 cvt_pk_bf16(float lo, float hi) {
  u32 r;
  asm("v_cvt_pk_bf16_f32 %0, %1, %2" : "=v"(r) : "v"(lo), "v"(hi));
  return r;
}

// v_permlane32_swap_b32 x, y: swaps x's lanes 32-63 with y's lanes 0-31.
__device__ __forceinline__ void swap32(u32& x, u32& y) {
  asm("v_permlane32_swap_b32 %0, %1" : "+v"(x), "+v"(y));
}

// async global->LDS, 16B per lane. LDS dest is wave-uniform base + lane*16.
__device__ __forceinline__ void gload_lds16(const bf16_t* g, bf16_t* l) {
  __builtin_amdgcn_global_load_lds(
      (const __attribute__((address_space(1))) unsigned int*)g,
      (__attribute__((address_space(3))) unsigned int*)l, 16, 0, 0);
}

// cvt 8 fp32 (two float4) -> bf16x8
__device__ __forceinline__ bf16x8 cvt8(float4 x0, float4 x1) {
  bf16x8 r;
  r[0] = (bf16_t)x0.x; r[1] = (bf16_t)x0.y; r[2] = (bf16_t)x0.z; r[3] = (bf16_t)x0.w;
  r[4] = (bf16_t)x1.x; r[5] = (bf16_t)x1.y; r[6] = (bf16_t)x1.z; r[7] = (bf16_t)x1.w;
  return r;
}

// Prepass: V fp32 [bh][s][d] -> Vt bf16 [bh][d][s] (64x64 tile transpose).
__global__ void prepass_kernel(const float* __restrict__ v,
                               bf16_t* __restrict__ vt) {
  __shared__ float tile[64][65];
  const int bh = blockIdx.y, kt = blockIdx.x;
  const float* vp = v + ((size_t)bh * S_ + (size_t)kt * 64) * D_;
  int r0 = threadIdx.x >> 4;
  int c4 = (threadIdx.x & 15) * 4;
#pragma unroll
  for (int p = 0; p < 4; ++p) {
    int r = r0 + p * 16;
    float4 x = *(const float4*)(vp + (size_t)r * D_ + c4);
    tile[r][c4 + 0] = x.x; tile[r][c4 + 1] = x.y;
    tile[r][c4 + 2] = x.z; tile[r][c4 + 3] = x.w;
  }
  __syncthreads();
  bf16_t* op = vt + (size_t)bh * D_ * S_ + (size_t)kt * 64;
#pragma unroll
  for (int p = 0; p < 4; ++p) {
    int d = r0 + p * 16;
    bf16x4 o = { (bf16_t)tile[c4 + 0][d], (bf16_t)tile[c4 + 1][d],
                 (bf16_t)tile[c4 + 2][d], (bf16_t)tile[c4 + 3][d] };
    *(bf16x4*)(op + (size_t)d * S_ + c4) = o;
  }
}

// Main kernel. 512 threads = 8 waves; wave (wq, wkv) owns q-rows wq*32..+31
// and KV tiles of parity wkv. 32x32x16 MFMA layouts (m74/m101):
//   A: lane holds A[lane&31][(lane>>5)*8 + j]; B: B[(lane>>5)*8+j][lane&31]
//   C/D: lane holds D[(reg&3) + 8*(reg>>2) + 4*(lane>>5)][lane&31]
// Swapped QK^T: S^T[kv][q] = mfma(A=K, B=Q^T) -> P per-lane for q = lane&31.
// PV transposed: O^T[d][q] = mfma(A=V^T, B=P^T); B-frag slot (hi,j) for
// k-step kt2 holds kv = 16*kt2 + 8*hi + j via the permlane32 half-exchange.
// K staging (in-kernel cvt): thread owns bf16 chunk (tid&7) of row tid>>3;
// fp32 source is linear (2 coalesced float4), LDS write goes to chunk
// (tid&7)^(row&7) — same involution the readers use.
// V staging: gload_lds, XOR swizzle on the source, linear LDS dest.
// XCD swizzle: bh = 4*(bid&7) + ((bid>>3)>>4), qt = (bid>>3)&15 (bijective).
__global__ __launch_bounds__(512, 4) void attn_kernel(
    const float* __restrict__ q, const float* __restrict__ kf,
    const bf16_t* __restrict__ vt, float* __restrict__ out) {
  const int bid = blockIdx.x;
  const int g = bid >> 3;
  const int bh = 4 * (bid & 7) + (g >> 4);
  const int qt = g & 15;
  const int tid = threadIdx.x;
  const int wid = tid >> 6;
  const int lane = tid & 63;
  const int wq = wid & 3;    // q-group
  const int wkv = wid >> 2;  // kv parity group
  const int l31 = lane & 31; // q column (QK^T) / row index
  const int hi = lane >> 5;  // lane half

  // 64 KB: K bufs [4][64][64] + V bufs [4][64][64]; epilogue aliases front.
  __shared__ __align__(16) char smem[65536];
  bf16_t* kbuf = (bf16_t*)smem;            // 4 x 4096 elems
  bf16_t* vbuf = (bf16_t*)(smem + 32768);  // 4 x 4096 elems
  float* epi = (float*)smem;               // [4][64][33] = 33.8 KB (aliases)

  const float* kp32 = kf + (size_t)bh * S_ * D_;
  const bf16_t* vp = vt + (size_t)bh * D_ * S_;

  // staging geometry
  const int srow = tid >> 3;
  const int sc = tid & 7;
  const int kofs32 = srow * D_ + sc * 8;                    // fp32 elems (linear)
  const int kwofs = srow * D_ + ((sc ^ (srow & 7)) * 8);    // bf16 elems (swz)
  const size_t vofs = (size_t)srow * S_ + (size_t)(sc ^ (srow & 7)) * 8;
  const int ldst = wid * 512;  // elems, wave-uniform V dest (wave covers 512)

  // Q B-fragments: lane holds Q[qrow][ks*16 + hi*8 + j] * 0.125*log2(e)
  const float qscale = 0.125f * 1.4426950408889634f;
  const int qrow = qt * QBLK + wq * 32 + l31;
  const float* qpr = q + ((size_t)bh * S_ + qrow) * D_;
  bf16x8 bq[4];
#pragma unroll
  for (int ks = 0; ks < 4; ++ks) {
    const float* p = qpr + ks * 16 + hi * 8;
    float4 x0 = *(const float4*)(p);
    float4 x1 = *(const float4*)(p + 4);
    bf16x8 a;
    a[0] = (bf16_t)(x0.x * qscale); a[1] = (bf16_t)(x0.y * qscale);
    a[2] = (bf16_t)(x0.z * qscale); a[3] = (bf16_t)(x0.w * qscale);
    a[4] = (bf16_t)(x1.x * qscale); a[5] = (bf16_t)(x1.y * qscale);
    a[6] = (bf16_t)(x1.z * qscale); a[7] = (bf16_t)(x1.w * qscale);
    bq[ks] = a;
  }

  float lsum = 0.f;
  f32x16 o0, o1;
#pragma unroll
  for (int r = 0; r < 16; ++r) { o0[r] = 0.f; o1[r] = 0.f; }

  // prologue: K tiles 0,1 converted synchronously; V tiles 0,1 async
#pragma unroll
  for (int par = 0; par < 2; ++par) {
    const float* kg = kp32 + (size_t)par * (KVBLK * D_) + kofs32;
    float4 x0 = *(const float4*)(kg);
    float4 x1 = *(const float4*)(kg + 4);
    *(bf16x8*)(kbuf + par * 4096 + kwofs) = cvt8(x0, x1);
    gload_lds16(vp + (size_t)par * KVBLK + vofs, vbuf + par * 4096 + ldst);
  }
  __syncthreads();

  for (int p = 0; p < NPER; ++p) {
    // T14 early-issue: K fp32 for next pair -> regs, PINNED here by the
    // memory fence (prevents the compiler sinking the loads to their use
    // point at period end — R12's failure). V gloads follow.
    float4 kx00, kx01, kx10, kx11;
    const int nb = ((p + 1) & 1) * 2;
    if (p + 1 < NPER) {
      const float* kg0 = kp32 + (size_t)(2 * p + 2) * (KVBLK * D_) + kofs32;
      const float* kg1 = kp32 + (size_t)(2 * p + 3) * (KVBLK * D_) + kofs32;
      kx00 = *(const float4*)(kg0); kx01 = *(const float4*)(kg0 + 4);
      kx10 = *(const float4*)(kg1); kx11 = *(const float4*)(kg1 + 4);
      asm volatile("" ::: "memory");  // pin load issue point
#pragma unroll
      for (int par = 0; par < 2; ++par)
        gload_lds16(vp + (size_t)(2 * p + 2 + par) * KVBLK + vofs,
                    vbuf + (nb + par) * 4096 + ldst);
    }

    const bf16_t* kt_ = kbuf + ((p & 1) * 2 + wkv) * 4096;
    const bf16_t* vt_ = vbuf + ((p & 1) * 2 + wkv) * 4096;

    u32 w[2][8];
#pragma unroll
    for (int sub = 0; sub < 2; ++sub) {
      // QK^T: S^T[32 kv][32 q], K from LDS rows sub*32 + l31
      f32x16 sv;
#pragma unroll
      for (int r = 0; r < 16; ++r) sv[r] = 0.f;
#pragma unroll
      for (int ks = 0; ks < 4; ++ks) {
        const int row = sub * 32 + l31;
        const int ch = (2 * ks + hi) ^ (row & 7);
        bf16x8 a = *(const bf16x8*)(kt_ + row * D_ + ch * 8);
        sv = mfma32(a, bq[ks], sv);
      }
      // softmax (fixed offset): e = exp2(s); pack pairs to bf16 words
#pragma unroll
      for (int b = 0; b < 4; ++b) {
        float e0 = __builtin_amdgcn_exp2f(sv[4 * b + 0]);
        float e1 = __builtin_amdgcn_exp2f(sv[4 * b + 1]);
        float e2 = __builtin_amdgcn_exp2f(sv[4 * b + 2]);
        float e3 = __builtin_amdgcn_exp2f(sv[4 * b + 3]);
        lsum += (e0 + e1) + (e2 + e3);
        w[sub][2 * b + 0] = cvt_pk_bf16(e0, e1);
        w[sub][2 * b + 1] = cvt_pk_bf16(e2, e3);
      }
      // half-exchange so each lane holds its PV B-frag words
#pragma unroll
      for (int kt2 = 0; kt2 < 2; ++kt2) {
        swap32(w[sub][4 * kt2 + 0], w[sub][4 * kt2 + 2]);
        swap32(w[sub][4 * kt2 + 1], w[sub][4 * kt2 + 3]);
      }
    }

    // PV: O^T[d][q] += V^T[d][kv] * P^T[kv][q]
#pragma unroll
    for (int sub = 0; sub < 2; ++sub)
#pragma unroll
      for (int kt2 = 0; kt2 < 2; ++kt2) {
        union { u32 u[4]; bf16x8 v; } pb;
        pb.u[0] = w[sub][4 * kt2 + 0]; pb.u[1] = w[sub][4 * kt2 + 1];
        pb.u[2] = w[sub][4 * kt2 + 2]; pb.u[3] = w[sub][4 * kt2 + 3];
        {
          const int row = l31;  // dblk 0
          const int ch = (4 * sub + 2 * kt2 + hi) ^ (row & 7);
          bf16x8 a = *(const bf16x8*)(vt_ + row * KVBLK + ch * 8);
          o0 = mfma32(a, pb.v, o0);
        }
        {
          const int row = 32 + l31;  // dblk 1
          const int ch = (4 * sub + 2 * kt2 + hi) ^ (row & 7);
          bf16x8 a = *(const bf16x8*)(vt_ + row * KVBLK + ch * 8);
          o1 = mfma32(a, pb.v, o1);
        }
      }

    // T14 write-late: cvt prefetched K -> next K buffers (last read @p-1,
    // barrier passed; readers wait for the barrier below).
    if (p + 1 < NPER) {
      *(bf16x8*)(kbuf + nb * 4096 + kwofs) = cvt8(kx00, kx01);
      *(bf16x8*)(kbuf + (nb + 1) * 4096 + kwofs) = cvt8(kx10, kx11);
    }

    // barrier: drains vmcnt+lgkmcnt (staged tiles ready) + all done with cur
    __syncthreads();
  }

  // ---- epilogue: combine kv-groups (pure addition: fixed-offset softmax)
  if (wkv == 1) {
    float* e = epi + ((size_t)wq * 64 + lane) * 33;
#pragma unroll
    for (int r = 0; r < 16; ++r) { e[r] = o0[r]; e[16 + r] = o1[r]; }
    e[32] = lsum;
  }
  __syncthreads();
  if (wkv == 0) {
    const float* e = epi + ((size_t)wq * 64 + lane) * 33;
#pragma unroll
    for (int r = 0; r < 16; ++r) { o0[r] += e[r]; o1[r] += e[16 + r]; }
    lsum += e[32];
    float ltot = lsum + __shfl_xor(lsum, 32, 64);
    float inv = 1.f / ltot;
    float* op = out + ((size_t)bh * S_ + qrow) * D_;
    // lane holds O^T[d = dblk*32 + 8b + 4hi + a][q = l31], a=0..3 consecutive
#pragma unroll
    for (int b = 0; b < 4; ++b) {
      float4 w0 = { o0[4 * b + 0] * inv, o0[4 * b + 1] * inv,
                    o0[4 * b + 2] * inv, o0[4 * b + 3] * inv };
      *(float4*)(op + 8 * b + 4 * hi) = w0;
      float4 w1 = { o1[4 * b + 0] * inv, o1[4 * b + 1] * inv,
                    o1[4 * b + 2] * inv, o1[4 * b + 3] * inv };
      *(float4*)(op + 32 + 8 * b + 4 * hi) = w1;
    }
  }
}

extern "C" void kernel_launch(void* const* d_in, const int* in_sizes, int n_in,
                              void* d_out, int out_size, void* d_ws, size_t ws_size,
                              hipStream_t stream) {
  const float* q = (const float*)d_in[0];
  const float* k = (const float*)d_in[1];
  const float* v = (const float*)d_in[2];
  float* out = (float*)d_out;

  // workspace: Vt (bf16 [BH][D][S]) = 8 MiB
  bf16_t* vt = (bf16_t*)d_ws;

  prepass_kernel<<<dim3(S_ / 64, BH_), 256, 0, stream>>>(v, vt);
  attn_kernel<<<dim3(BH_ * (S_ / QBLK)), 512, 0, stream>>>(q, k, vt, out);
}

// Round 17
// 55.748 us; speedup vs baseline: 4.0523x; 1.3119x over previous
//
#include <hip/hip_runtime.h>
#include <hip/hip_bf16.h>
#include <stdint.h>

// Attention (non-causal): B=2 H=16 S=2048 D=64, fp32 in/out.
// R17 = R11 restored verbatim — the verified best (55.8us total, attn 46.5us).
// Structure: 8 waves x 32 q-rows, wave-level KV split (even/odd tiles;
// fixed-offset softmax makes partials additive), 32x32x16 MFMA, in-register
// P via v_cvt_pk_bf16_f32 + v_permlane32_swap_b32, global_load_lds staging
// w/ XOR source swizzle, XCD-aware block swizzle, fused K/V prepass,
// 16 MFMA per wave per barrier-period.
// Closed (measured) levers: setprio (R10, -3.5us), kv-half split (R9, -29),
// fatter waves (R5, -10), bank pad (R13, null: 4cyc/b128 is the structural
// floor), cross-period PV pipeline (R14, null), fused spin-gate (R15, -170),
// in-kernel K cvt with/without load-pin (R12/R16, -25). Prepass at BW floor.

#define B_ 2
#define H_ 16
#define S_ 2048
#define D_ 64
#define BH_ (B_ * H_)
#define QBLK 128
#define KVBLK 64
#define NKV (S_ / KVBLK)   // 32
#define NPER (NKV / 2)     // 16 periods, 2 tiles each

typedef __bf16 bf16_t;
typedef bf16_t bf16x8 __attribute__((ext_vector_type(8)));
typedef bf16_t bf16x4 __attribute__((ext_vector_type(4)));
typedef float f32x16 __attribute__((ext_vector_type(16)));
typedef uint32_t u32;

__device__ __forceinline__ f32x16 mfma32(bf16x8 a, bf16x8 b, f32x16 c) {
  return __builtin_amdgcn_mfma_f32_32x32x16_bf16(a, b, c, 0, 0, 0);
}

// pack two f32 -> u32 of 2 bf16 (lo in low 16 bits). No builtin on gfx950.
__device__ __forceinline__ u32 cvt_pk_bf16(float lo, float hi) {
  u32 r;
  asm("v_cvt_pk_bf16_f32 %0, %1, %2" : "=v"(r) : "v"(lo), "v"(hi));
  return r;
}

// v_permlane32_swap_b32 x, y: swaps x's lanes 32-63 with y's lanes 0-31.
__device__ __forceinline__ void swap32(u32& x, u32& y) {
  asm("v_permlane32_swap_b32 %0, %1" : "+v"(x), "+v"(y));
}

// async global->LDS, 16B per lane. LDS dest is wave-uniform base + lane*16.
__device__ __forceinline__ void gload_lds16(const bf16_t* g, bf16_t* l) {
  __builtin_amdgcn_global_load_lds(
      (const __attribute__((address_space(1))) unsigned int*)g,
      (__attribute__((address_space(3))) unsigned int*)l, 16, 0, 0);
}

// Fused prepass: z=0 -> K fp32 [bh][s][d] -> Kb bf16 (same layout);
//                z=1 -> V fp32 [bh][s][d] -> Vt bf16 [bh][d][s] (transpose).
__global__ void prepass_kernel(const float* __restrict__ k,
                               const float* __restrict__ v,
                               bf16_t* __restrict__ kb,
                               bf16_t* __restrict__ vt) {
  __shared__ float tile[64][65];
  const int bh = blockIdx.y, kt = blockIdx.x;
  if (blockIdx.z == 0) {
    // convert one 64x64 fp32 K tile -> bf16 (flat, coalesced)
    const float* src = k + ((size_t)bh * S_ + (size_t)kt * 64) * D_;
    bf16_t* dst = kb + ((size_t)bh * S_ + (size_t)kt * 64) * D_;
#pragma unroll
    for (int i = 0; i < 4; ++i) {
      int idx = i * 256 + threadIdx.x;  // float4 index, coalesced per i
      float4 x = ((const float4*)src)[idx];
      bf16x4 o = { (bf16_t)x.x, (bf16_t)x.y, (bf16_t)x.z, (bf16_t)x.w };
      *(bf16x4*)(dst + (size_t)idx * 4) = o;
    }
  } else {
    // transpose one 64x64 V tile via LDS
    const float* vp = v + ((size_t)bh * S_ + (size_t)kt * 64) * D_;
    int r0 = threadIdx.x >> 4;        // 0..15
    int c4 = (threadIdx.x & 15) * 4;  // 0..60
#pragma unroll
    for (int p = 0; p < 4; ++p) {
      int r = r0 + p * 16;
      float4 x = *(const float4*)(vp + (size_t)r * D_ + c4);
      tile[r][c4 + 0] = x.x; tile[r][c4 + 1] = x.y;
      tile[r][c4 + 2] = x.z; tile[r][c4 + 3] = x.w;
    }
    __syncthreads();
    bf16_t* op = vt + (size_t)bh * D_ * S_ + (size_t)kt * 64;
#pragma unroll
    for (int p = 0; p < 4; ++p) {
      int d = r0 + p * 16;
      bf16x4 o = { (bf16_t)tile[c4 + 0][d], (bf16_t)tile[c4 + 1][d],
                   (bf16_t)tile[c4 + 2][d], (bf16_t)tile[c4 + 3][d] };
      *(bf16x4*)(op + (size_t)d * S_ + c4) = o;
    }
  }
}

// Main kernel. 512 threads = 8 waves; wave (wq, wkv) owns q-rows wq*32..+31
// and KV tiles of parity wkv. 32x32x16 MFMA layouts (m74/m101):
//   A: lane holds A[lane&31][(lane>>5)*8 + j]; B: B[(lane>>5)*8+j][lane&31]
//   C/D: lane holds D[(reg&3) + 8*(reg>>2) + 4*(lane>>5)][lane&31]
// Swapped QK^T: S^T[kv][q] = mfma(A=K, B=Q^T) -> P per-lane for q = lane&31.
// PV transposed: O^T[d][q] = mfma(A=V^T, B=P^T); B-frag slot (hi,j) for
// k-step kt2 holds kv = 16*kt2 + 8*hi + j via the permlane32 half-exchange.
// XCD swizzle: bh = 4*(bid&7) + ((bid>>3)>>4), qt = (bid>>3)&15 (bijective):
// all 16 q-tile blocks of one bh land on one XCD -> K/V stay in that L2.
__global__ __launch_bounds__(512, 4) void attn_kernel(
    const float* __restrict__ q, const bf16_t* __restrict__ kb,
    const bf16_t* __restrict__ vt, float* __restrict__ out) {
  const int bid = blockIdx.x;
  const int g = bid >> 3;
  const int bh = 4 * (bid & 7) + (g >> 4);
  const int qt = g & 15;
  const int tid = threadIdx.x;
  const int wid = tid >> 6;
  const int lane = tid & 63;
  const int wq = wid & 3;    // q-group
  const int wkv = wid >> 2;  // kv parity group
  const int l31 = lane & 31; // q column (QK^T) / row index
  const int hi = lane >> 5;  // lane half

  // 64 KB: K bufs [per][par][64][64] + V bufs; epilogue aliases the front.
  __shared__ __align__(16) char smem[65536];
  bf16_t* kbuf = (bf16_t*)smem;            // 4 x 4096 elems
  bf16_t* vbuf = (bf16_t*)(smem + 32768);  // 4 x 4096 elems
  float* epi = (float*)smem;               // [4][64][33] = 33.8 KB (aliases)

  const bf16_t* kp = kb + (size_t)bh * S_ * D_;
  const bf16_t* vp = vt + (size_t)bh * D_ * S_;

  // staging geometry: thread covers 16B chunk tid of each 8KB tile
  const int srow = tid >> 3;
  const int scol = (tid & 7) ^ (srow & 7);  // XOR chunk swizzle (source side)
  const int kofs = srow * D_ + scol * 8;
  const size_t vofs = (size_t)srow * S_ + scol * 8;
  const int ldst = wid * 512;  // elems, wave-uniform dest (wave covers 512)

  // Q B-fragments: lane holds Q[qrow][ks*16 + hi*8 + j] * 0.125*log2(e)
  const float qscale = 0.125f * 1.4426950408889634f;
  const int qrow = qt * QBLK + wq * 32 + l31;
  const float* qpr = q + ((size_t)bh * S_ + qrow) * D_;
  bf16x8 bq[4];
#pragma unroll
  for (int ks = 0; ks < 4; ++ks) {
    const float* p = qpr + ks * 16 + hi * 8;
    float4 x0 = *(const float4*)(p);
    float4 x1 = *(const float4*)(p + 4);
    bf16x8 a;
    a[0] = (bf16_t)(x0.x * qscale); a[1] = (bf16_t)(x0.y * qscale);
    a[2] = (bf16_t)(x0.z * qscale); a[3] = (bf16_t)(x0.w * qscale);
    a[4] = (bf16_t)(x1.x * qscale); a[5] = (bf16_t)(x1.y * qscale);
    a[6] = (bf16_t)(x1.z * qscale); a[7] = (bf16_t)(x1.w * qscale);
    bq[ks] = a;
  }

  float lsum = 0.f;
  f32x16 o0, o1;
#pragma unroll
  for (int r = 0; r < 16; ++r) { o0[r] = 0.f; o1[r] = 0.f; }

  // prologue: stage tiles 0,1 into parity-buf 0
#pragma unroll
  for (int par = 0; par < 2; ++par) {
    gload_lds16(kp + (size_t)par * (KVBLK * D_) + kofs, kbuf + par * 4096 + ldst);
    gload_lds16(vp + (size_t)par * KVBLK + vofs, vbuf + par * 4096 + ldst);
  }
  __syncthreads();

  for (int p = 0; p < NPER; ++p) {
    // stage next tile pair into the other parity buffers
    if (p + 1 < NPER) {
      const int nb = ((p + 1) & 1) * 2;
#pragma unroll
      for (int par = 0; par < 2; ++par) {
        const int t = 2 * p + 2 + par;
        gload_lds16(kp + (size_t)t * (KVBLK * D_) + kofs,
                    kbuf + (nb + par) * 4096 + ldst);
        gload_lds16(vp + (size_t)t * KVBLK + vofs,
                    vbuf + (nb + par) * 4096 + ldst);
      }
    }

    const bf16_t* kt_ = kbuf + ((p & 1) * 2 + wkv) * 4096;
    const bf16_t* vt_ = vbuf + ((p & 1) * 2 + wkv) * 4096;

    u32 w[2][8];
#pragma unroll
    for (int sub = 0; sub < 2; ++sub) {
      // QK^T: S^T[32 kv][32 q], K from LDS rows sub*32 + l31
      f32x16 sv;
#pragma unroll
      for (int r = 0; r < 16; ++r) sv[r] = 0.f;
#pragma unroll
      for (int ks = 0; ks < 4; ++ks) {
        const int row = sub * 32 + l31;
        const int ch = (2 * ks + hi) ^ (row & 7);
        bf16x8 a = *(const bf16x8*)(kt_ + row * D_ + ch * 8);
        sv = mfma32(a, bq[ks], sv);
      }
      // softmax (fixed offset): e = exp2(s); pack pairs to bf16 words
#pragma unroll
      for (int b = 0; b < 4; ++b) {
        float e0 = __builtin_amdgcn_exp2f(sv[4 * b + 0]);
        float e1 = __builtin_amdgcn_exp2f(sv[4 * b + 1]);
        float e2 = __builtin_amdgcn_exp2f(sv[4 * b + 2]);
        float e3 = __builtin_amdgcn_exp2f(sv[4 * b + 3]);
        lsum += (e0 + e1) + (e2 + e3);
        w[sub][2 * b + 0] = cvt_pk_bf16(e0, e1);
        w[sub][2 * b + 1] = cvt_pk_bf16(e2, e3);
      }
      // half-exchange so each lane holds its PV B-frag words
#pragma unroll
      for (int kt2 = 0; kt2 < 2; ++kt2) {
        swap32(w[sub][4 * kt2 + 0], w[sub][4 * kt2 + 2]);
        swap32(w[sub][4 * kt2 + 1], w[sub][4 * kt2 + 3]);
      }
    }

    // PV: O^T[d][q] += V^T[d][kv] * P^T[kv][q]
#pragma unroll
    for (int sub = 0; sub < 2; ++sub)
#pragma unroll
      for (int kt2 = 0; kt2 < 2; ++kt2) {
        union { u32 u[4]; bf16x8 v; } pb;
        pb.u[0] = w[sub][4 * kt2 + 0]; pb.u[1] = w[sub][4 * kt2 + 1];
        pb.u[2] = w[sub][4 * kt2 + 2]; pb.u[3] = w[sub][4 * kt2 + 3];
        {
          const int row = l31;  // dblk 0
          const int ch = (4 * sub + 2 * kt2 + hi) ^ (row & 7);
          bf16x8 a = *(const bf16x8*)(vt_ + row * KVBLK + ch * 8);
          o0 = mfma32(a, pb.v, o0);
        }
        {
          const int row = 32 + l31;  // dblk 1
          const int ch = (4 * sub + 2 * kt2 + hi) ^ (row & 7);
          bf16x8 a = *(const bf16x8*)(vt_ + row * KVBLK + ch * 8);
          o1 = mfma32(a, pb.v, o1);
        }
      }

    // barrier: drains vmcnt (next tiles staged) + all waves done with cur
    __syncthreads();
  }

  // ---- epilogue: combine kv-groups (pure addition: fixed-offset softmax)
  if (wkv == 1) {
    float* e = epi + ((size_t)wq * 64 + lane) * 33;
#pragma unroll
    for (int r = 0; r < 16; ++r) { e[r] = o0[r]; e[16 + r] = o1[r]; }
    e[32] = lsum;
  }
  __syncthreads();
  if (wkv == 0) {
    const float* e = epi + ((size_t)wq * 64 + lane) * 33;
#pragma unroll
    for (int r = 0; r < 16; ++r) { o0[r] += e[r]; o1[r] += e[16 + r]; }
    lsum += e[32];
    float ltot = lsum + __shfl_xor(lsum, 32, 64);
    float inv = 1.f / ltot;
    float* op = out + ((size_t)bh * S_ + qrow) * D_;
    // lane holds O^T[d = dblk*32 + 8b + 4hi + a][q = l31], a=0..3 consecutive
#pragma unroll
    for (int b = 0; b < 4; ++b) {
      float4 w0 = { o0[4 * b + 0] * inv, o0[4 * b + 1] * inv,
                    o0[4 * b + 2] * inv, o0[4 * b + 3] * inv };
      *(float4*)(op + 8 * b + 4 * hi) = w0;
      float4 w1 = { o1[4 * b + 0] * inv, o1[4 * b + 1] * inv,
                    o1[4 * b + 2] * inv, o1[4 * b + 3] * inv };
      *(float4*)(op + 32 + 8 * b + 4 * hi) = w1;
    }
  }
}

extern "C" void kernel_launch(void* const* d_in, const int* in_sizes, int n_in,
                              void* d_out, int out_size, void* d_ws, size_t ws_size,
                              hipStream_t stream) {
  const float* q = (const float*)d_in[0];
  const float* k = (const float*)d_in[1];
  const float* v = (const float*)d_in[2];
  float* out = (float*)d_out;

  // workspace: Kb (bf16 [BH][S][D]) + Vt (bf16 [BH][D][S]) = 16 MiB total
  bf16_t* kb = (bf16_t*)d_ws;
  bf16_t* vt = kb + (size_t)BH_ * S_ * D_;

  prepass_kernel<<<dim3(S_ / 64, BH_, 2), 256, 0, stream>>>(k, v, kb, vt);
  attn_kernel<<<dim3(BH_ * (S_ / QBLK)), 512, 0, stream>>>(q, kb, vt, out);
}